// Round 4
// baseline (1365.531 us; speedup 1.0000x reference)
//
#include <hip/hip_runtime.h>
#include <hip/hip_bf16.h>

// ---------- types ----------
typedef __bf16 bf16x8 __attribute__((ext_vector_type(8)));
typedef float  f32x4  __attribute__((ext_vector_type(4)));
typedef unsigned int u32x4 __attribute__((ext_vector_type(4)));
typedef unsigned short u16x8 __attribute__((ext_vector_type(8)));

__device__ inline unsigned short f2bf(float f) {
    union { __hip_bfloat16 h; unsigned short u; } cv;
    cv.h = __float2bfloat16(f);
    return cv.u;
}

// load 8 bf16 = two 8B halves at col +0 and col +16 (k-halves of 16x16x32)
__device__ inline bf16x8 load8(const unsigned short* p) {
    uint2 lo = *(const uint2*)(p);
    uint2 hi = *(const uint2*)(p + 16);
    u32x4 v; v[0] = lo.x; v[1] = lo.y; v[2] = hi.x; v[3] = hi.y;
    return __builtin_bit_cast(bf16x8, v);
}

__device__ inline f32x4 mfma16(bf16x8 a, bf16x8 b, f32x4 c) {
    return __builtin_amdgcn_mfma_f32_16x16x32_bf16(a, b, c, 0, 0, 0);
}

// window-row (global, 0..148959) -> spatial token (0..131071); false if pad
__device__ inline bool winmapT(int gg, int& T) {
    int win = gg / 98, n = gg % 98;
    int wdi = win / 190, rem = win % 190, whi = rem / 19, wwi = rem % 19;
    int td = n / 49, th = (n / 7) % 7, tw = n % 7;
    int sd = (wdi * 2 + td + 1) & 15;
    int sh = whi * 7 + th + 3; if (sh >= 70) sh -= 70;
    int sw = wwi * 7 + tw + 3; if (sw >= 133) sw -= 133;
    if (sh < 64 && sw < 128) { T = (sd * 64 + sh) * 128 + sw; return true; }
    return false;
}

// ---------- K0: mod = silu(t) @ wa1 @ wa2 + ba2  (1152 floats) ----------
__global__ __launch_bounds__(256) void mod_k(const float* __restrict__ t,
    const float* __restrict__ wa1, const float* __restrict__ wa2,
    const float* __restrict__ ba2, float* __restrict__ mod)
{
    __shared__ float st[192];
    __shared__ float a[24];
    int tid = threadIdx.x;
    if (tid < 192) { float x = t[tid]; st[tid] = x / (1.f + __expf(-x)); }
    __syncthreads();
    if (tid < 24) {
        float s = 0.f;
        for (int c = 0; c < 192; ++c) s += st[c] * wa1[c * 24 + tid];
        a[tid] = s;
    }
    __syncthreads();
    for (int j = tid; j < 1152; j += 256) {
        float s = ba2[j];
        for (int r = 0; r < 24; ++r) s += a[r] * wa2[r * 1152 + j];
        mod[j] = s;
    }
}

// ---------- K1: weight transposes (fp32 -> bf16, [N][K]) + bias table ----------
__global__ __launch_bounds__(256) void prep_k(
    const float* __restrict__ wqkv, const float* __restrict__ wproj,
    const float* __restrict__ w1, const float* __restrict__ w2,
    const float* __restrict__ relb,
    unsigned short* __restrict__ wqkvT, unsigned short* __restrict__ wprojT,
    unsigned short* __restrict__ w1T, unsigned short* __restrict__ w2T,
    float* __restrict__ bias6)
{
    int i = blockIdx.x * 256 + threadIdx.x;
    if (i < 110592) { int n = i / 192, k = i % 192; wqkvT[i] = f2bf(wqkv[k * 576 + n]); return; }
    i -= 110592;
    if (i < 36864)  { int n = i / 192, k = i % 192; wprojT[i] = f2bf(wproj[k * 192 + n]); return; }
    i -= 36864;
    if (i < 147456) { int n = i / 192, k = i % 192; w1T[i] = f2bf(w1[k * 768 + n]); return; }
    i -= 147456;
    if (i < 147456) { int n = i / 768, k = i % 768; w2T[i] = f2bf(w2[k * 192 + n]); return; }
    i -= 147456;
    if (i < 57624) {
        int h = i / 9604, rm = i % 9604, n = rm / 98, m = rm % 98;
        int tdn = n / 49, thn = (n / 7) % 7, twn = n % 7;
        int tdm = m / 49, thm = (m / 7) % 7, twm = m % 7;
        int idx = (tdn - tdm + 1) * 169 + (thn - thm + 6) * 13 + (twn - twm + 6);
        bias6[i] = relb[idx * 6 + h];
    }
}

// ---------- stats: per-token LN mean/rstd over fp32 [tok][192] ----------
__global__ __launch_bounds__(256) void stats_f32_k(const float* __restrict__ x,
    float* __restrict__ st)
{
    int tok = blockIdx.x * 4 + (threadIdx.x >> 6);
    int lane = threadIdx.x & 63;
    const float* p = x + (size_t)tok * 192;
    float a = p[lane], b = p[64 + lane], c = p[128 + lane];
    float s = a + b + c, q = a * a + b * b + c * c;
    for (int m = 32; m; m >>= 1) { s += __shfl_xor(s, m); q += __shfl_xor(q, m); }
    if (lane == 0) {
        float mean = s * (1.f / 192.f);
        float var  = q * (1.f / 192.f) - mean * mean;
        st[2 * tok] = mean;
        st[2 * tok + 1] = rsqrtf(var + 1e-6f);
    }
}

// ---------- GEMM: C[M][N] = A[M][K](bf16) * BT[N][K]^T(bf16) + epilogue ----------
// 64x64 tile, 4 waves 2x2, each wave 32x32 via 2x2 frags of 16x16x32.
// STAGE: 0 = A is plain bf16 [M][K] chunk-local rows
//        1 = A is virtual modulate(LN(x)) via window gather; Af = x fp32, stats=stats1
//        2 = A is virtual modulate(LN(x1)); Af = x1 fp32 at global rows row0+g, stats=stats2
// EPI:   0 = bias -> bf16 outB (qkv chunk)
//        1 = bias + gelu -> bf16 outB (fc1 chunk)
//        2 = proj: scatter-residual -> fp32 outF (x1 = auxF + g*v), auxF = x fp32
//        3 = fc2: in-place final residual on fp32 outF at global rows
template<int STAGE, int EPI>
__global__ __launch_bounds__(256) void gemm_k(
    const unsigned short* __restrict__ A, const float* __restrict__ Af,
    const unsigned short* __restrict__ BT, const float* __restrict__ bias,
    unsigned short* __restrict__ outB, float* outF,
    const float* __restrict__ auxF, const float* __restrict__ stats,
    const float* __restrict__ mod, int row0, int M, int N, int K)
{
    __shared__ unsigned short As[64][56];   // row stride 112B
    __shared__ unsigned short Bs[64][56];
    const int t = threadIdx.x;
    const int m0 = blockIdx.x * 64, n0 = blockIdx.y * 64;
    const int lr = t >> 2, lk = (t & 3) * 8;
    const int wid = t >> 6, lane = t & 63;
    const int lg = lane >> 4, l16 = lane & 15;
    const int wm = (wid >> 1) * 32, wn = (wid & 1) * 32;
    f32x4 acc[2][2] = {};

    // hoisted per-row staging state
    const int g = m0 + lr;   // chunk-local row this thread stages
    bool v1 = false; size_t sbase = 0; float mn = 0.f, rs = 0.f;
    if (STAGE == 1) {
        int T;
        if (g < M && winmapT(row0 + g, T)) {
            v1 = true; sbase = (size_t)T * 192;
            mn = stats[2 * T]; rs = stats[2 * T + 1];
        }
    } else if (STAGE == 2) {
        int tok = row0 + g;
        sbase = (size_t)tok * 192;
        mn = stats[2 * tok]; rs = stats[2 * tok + 1];
    }

    for (int kk = 0; kk < K; kk += 32) {
        if (STAGE == 0) {
            u16x8 av = {0, 0, 0, 0, 0, 0, 0, 0};
            if (g < M) av = *(const u16x8*)(A + (size_t)g * K + kk + lk);
            *(u16x8*)(&As[lr][lk]) = av;
        } else if (STAGE == 1) {
            u16x8 o = {0, 0, 0, 0, 0, 0, 0, 0};
            if (v1) {
                float4 xa = *(const float4*)(Af + sbase + kk + lk);
                float4 xb = *(const float4*)(Af + sbase + kk + lk + 4);
                float xs[8] = {xa.x, xa.y, xa.z, xa.w, xb.x, xb.y, xb.z, xb.w};
                #pragma unroll
                for (int j = 0; j < 8; ++j) {
                    int c = kk + lk + j;
                    o[j] = f2bf((xs[j] - mn) * rs * (1.f + mod[192 + c]) + mod[c]);
                }
            }
            *(u16x8*)(&As[lr][lk]) = o;
        } else { // STAGE 2: modulate(LN2(x1)) from fp32 x1
            float4 xa = *(const float4*)(Af + sbase + kk + lk);
            float4 xb = *(const float4*)(Af + sbase + kk + lk + 4);
            float xs[8] = {xa.x, xa.y, xa.z, xa.w, xb.x, xb.y, xb.z, xb.w};
            u16x8 o;
            #pragma unroll
            for (int j = 0; j < 8; ++j) {
                int c = kk + lk + j;
                o[j] = f2bf((xs[j] - mn) * rs * (1.f + mod[768 + c]) + mod[576 + c]);
            }
            *(u16x8*)(&As[lr][lk]) = o;
        }
        u16x8 bv = *(const u16x8*)(BT + (size_t)(n0 + lr) * K + kk + lk);
        *(u16x8*)(&Bs[lr][lk]) = bv;
        __syncthreads();
        bf16x8 af0 = load8(&As[wm + l16][4 * lg]);
        bf16x8 af1 = load8(&As[wm + 16 + l16][4 * lg]);
        bf16x8 bf0 = load8(&Bs[wn + l16][4 * lg]);
        bf16x8 bf1 = load8(&Bs[wn + 16 + l16][4 * lg]);
        acc[0][0] = mfma16(af0, bf0, acc[0][0]);
        acc[0][1] = mfma16(af0, bf1, acc[0][1]);
        acc[1][0] = mfma16(af1, bf0, acc[1][0]);
        acc[1][1] = mfma16(af1, bf1, acc[1][1]);
        __syncthreads();
    }

    #pragma unroll
    for (int i = 0; i < 2; ++i)
    #pragma unroll
    for (int j = 0; j < 2; ++j) {
        int gcol = n0 + wn + j * 16 + l16;
        float b = bias[gcol];
        #pragma unroll
        for (int e = 0; e < 4; ++e) {
            int grow = m0 + wm + i * 16 + lg * 4 + e;   // chunk-local
            if (grow >= M) continue;
            float v = acc[i][j][e] + b;
            if (EPI == 0) {
                outB[(size_t)grow * N + gcol] = f2bf(v);
            } else if (EPI == 1) {
                float gl = 0.5f * v * (1.f + erff(v * 0.70710678118654752f));
                outB[(size_t)grow * N + gcol] = f2bf(gl);
            } else if (EPI == 2) {
                int T;
                if (winmapT(row0 + grow, T)) {
                    size_t idx = (size_t)T * 192 + gcol;
                    outF[idx] = auxF[idx] + mod[384 + gcol] * v;
                }
            } else {
                size_t idx = (size_t)(row0 + grow) * 192 + gcol;
                outF[idx] = outF[idx] + mod[960 + gcol] * v;
            }
        }
    }
}

// ---------- attention, one block per (local window, head) ----------
__global__ __launch_bounds__(256) void attn_k(
    const unsigned short* __restrict__ qkv, const float* __restrict__ mask,
    const float* __restrict__ bias6, unsigned short* __restrict__ out)
{
    __shared__ __align__(16) char smem[78424];
    unsigned short* Sbf = (unsigned short*)smem;            // [112][136] bf16 (aliases Qs/Ks)
    unsigned short* VT  = (unsigned short*)(smem + 30464);  // [32][136]  bf16
    unsigned short* Qs  = (unsigned short*)smem;            // [112][40]  bf16
    unsigned short* Ks  = (unsigned short*)(smem + 8960);   // [112][40]  bf16
    float* S32  = (float*)(smem + 39168);                   // [98][99]
    float* rsum = (float*)(smem + 77976);                   // [98]

    const int blk = blockIdx.x;
    const int win = blk / 6, h = blk % 6;   // local window id
    const int t = threadIdx.x;
    const int wid = t >> 6, lane = t & 63, lg = lane >> 4, l16 = lane & 15;
    const size_t rb = (size_t)win * 98;

    // phase 1: stage Q, K rows, V^T; zero-fill pad rows
    for (int i = t; i < 98 * 4; i += 256) {
        int r = i >> 2, cg = (i & 3) * 8;
        *(float4*)(Qs + r * 40 + cg) = *(const float4*)(qkv + (rb + r) * 576 + h * 32 + cg);
        *(float4*)(Ks + r * 40 + cg) = *(const float4*)(qkv + (rb + r) * 576 + 192 + h * 32 + cg);
    }
    for (int i = t; i < 14 * 32; i += 256) {   // Q/K pad rows 98..111
        int r = 98 + (i >> 5), c = i & 31;
        Qs[r * 40 + c] = 0; Ks[r * 40 + c] = 0;
    }
    for (int i = t; i < 14 * 128; i += 256) {  // Sbf pad rows 98..111
        int r = 98 + (i >> 7), c = i & 127;
        Sbf[r * 136 + c] = 0;
    }
    for (int i = t; i < 32 * 38; i += 256) { int c = i / 38, m = 98 + i % 38; VT[c * 136 + m] = 0; }
    for (int i = t; i < 98 * 32; i += 256) {
        int m = i >> 5, c = i & 31;
        VT[c * 136 + m] = qkv[(rb + m) * 576 + 384 + h * 32 + c];
    }
    __syncthreads();

    // phase 2: S = Q K^T
    {
        bf16x8 kb[7];
        #pragma unroll
        for (int fn = 0; fn < 7; ++fn) kb[fn] = load8(Ks + (fn * 16 + l16) * 40 + 4 * lg);
        for (int fi = 0; fi < 2; ++fi) {
            int fm = wid + fi * 4;
            if (fm < 7) {
                bf16x8 qa = load8(Qs + (fm * 16 + l16) * 40 + 4 * lg);
                #pragma unroll
                for (int fn = 0; fn < 7; ++fn) {
                    f32x4 acc = {};
                    acc = mfma16(qa, kb[fn], acc);
                    #pragma unroll
                    for (int e = 0; e < 4; ++e) {
                        int r = fm * 16 + lg * 4 + e, c = fn * 16 + l16;
                        if (r < 98 && c < 98) S32[r * 99 + c] = acc[e];
                    }
                }
            }
        }
    }
    __syncthreads();

    // phase 3: softmax rows (scale + rel bias + mask), write bf16 P, keep row sums
    if (t < 98) {
        int r = t;
        const float* mrow = mask + (size_t)win * 9604 + r * 98;
        const float* brow = bias6 + (size_t)h * 9604 + r * 98;
        float mx = -1e30f;
        for (int c = 0; c < 98; ++c) {
            float s = S32[r * 99 + c] * 0.17677669529663687f + brow[c] + mrow[c];
            S32[r * 99 + c] = s;
            mx = fmaxf(mx, s);
        }
        float sum = 0.f;
        for (int c = 0; c < 98; ++c) {
            float e = __expf(S32[r * 99 + c] - mx);
            sum += e;
            Sbf[r * 136 + c] = f2bf(e);
        }
        for (int c = 98; c < 128; ++c) Sbf[r * 136 + c] = 0;
        rsum[r] = sum;
    }
    __syncthreads();

    // phase 4: O = P V
    for (int fi = 0; fi < 2; ++fi) {
        int fm = wid + fi * 4;
        if (fm < 7) {
            bf16x8 sa[4];
            #pragma unroll
            for (int ks = 0; ks < 4; ++ks)
                sa[ks] = load8(Sbf + (fm * 16 + l16) * 136 + ks * 32 + 4 * lg);
            #pragma unroll
            for (int fn = 0; fn < 2; ++fn) {
                f32x4 acc = {};
                #pragma unroll
                for (int ks = 0; ks < 4; ++ks) {
                    bf16x8 vb = load8(VT + (fn * 16 + l16) * 136 + ks * 32 + 4 * lg);
                    acc = mfma16(sa[ks], vb, acc);
                }
                #pragma unroll
                for (int e = 0; e < 4; ++e) {
                    int r = fm * 16 + lg * 4 + e;
                    if (r < 98) {
                        float val = acc[e] / rsum[r];
                        out[(rb + r) * 192 + h * 32 + fn * 16 + l16] = f2bf(val);
                    }
                }
            }
        }
    }
}

// ---------- launch ----------
// d_out is fp32 [131072][192]; it is ALSO the x1 buffer (proj writes x1 there,
// fc2 does the in-place final residual). Workspace span ~35.5 MB.
extern "C" void kernel_launch(void* const* d_in, const int* in_sizes, int n_in,
                              void* d_out, int out_size, void* d_ws, size_t ws_size,
                              hipStream_t stream)
{
    const float* x      = (const float*)d_in[0];
    const float* maskm  = (const float*)d_in[1];
    const float* tvec   = (const float*)d_in[2];
    const float* w_qkv  = (const float*)d_in[3];
    const float* b_qkv  = (const float*)d_in[4];
    const float* relb   = (const float*)d_in[5];
    const float* w_proj = (const float*)d_in[6];
    const float* b_proj = (const float*)d_in[7];
    const float* w1     = (const float*)d_in[8];
    const float* b1     = (const float*)d_in[9];
    const float* w2     = (const float*)d_in[10];
    const float* b2     = (const float*)d_in[11];
    const float* wa1    = (const float*)d_in[12];
    const float* wa2    = (const float*)d_in[13];
    const float* ba2    = (const float*)d_in[14];

    char* ws = (char*)d_ws;
    float*          mod    = (float*)ws;
    float*          stats1 = (float*)(ws + 4608);
    float*          stats2 = (float*)(ws + 1053184);
    unsigned short* wqkvT  = (unsigned short*)(ws + 2101760);
    unsigned short* wprojT = (unsigned short*)(ws + 2322944);
    unsigned short* w1T    = (unsigned short*)(ws + 2396672);
    unsigned short* w2T    = (unsigned short*)(ws + 2691584);
    float*          bias6  = (float*)(ws + 2986496);
    unsigned short* qkvb_c = (unsigned short*)(ws + 3216992);   // [18620][576] bf16
    unsigned short* hq_c   = (unsigned short*)(ws + 3216992);   // [16384][768] bf16 (aliases)
    unsigned short* attn_c = (unsigned short*)(ws + 28382816);  // [18620][192] bf16
    float*          dout   = (float*)d_out;                     // fp32 out == x1 buffer

    mod_k<<<1, 256, 0, stream>>>(tvec, wa1, wa2, ba2, mod);
    prep_k<<<1954, 256, 0, stream>>>(w_qkv, w_proj, w1, w2, relb, wqkvT, wprojT, w1T, w2T, bias6);
    stats_f32_k<<<32768, 256, 0, stream>>>(x, stats1);

    // qkv -> attention -> proj(+residual scatter into d_out as fp32 x1), 8 window-chunks
    for (int wc = 0; wc < 8; ++wc) {
        int r0 = wc * 18620;
        gemm_k<1, 0><<<dim3(291, 9), 256, 0, stream>>>(
            nullptr, x, wqkvT, b_qkv, qkvb_c, nullptr, nullptr, stats1, mod, r0, 18620, 576, 192);
        attn_k<<<1140, 256, 0, stream>>>(qkvb_c, maskm + (size_t)wc * 190 * 9604, bias6, attn_c);
        gemm_k<0, 2><<<dim3(291, 3), 256, 0, stream>>>(
            attn_c, nullptr, wprojT, b_proj, nullptr, dout, x, nullptr, mod, r0, 18620, 192, 192);
    }

    stats_f32_k<<<32768, 256, 0, stream>>>(dout, stats2);

    // MLP: fc1(+LN2 fused staging, gelu) -> fc2(in-place final residual on d_out), 8 chunks
    for (int q = 0; q < 8; ++q) {
        int r0 = q * 16384;
        gemm_k<2, 1><<<dim3(256, 12), 256, 0, stream>>>(
            nullptr, dout, w1T, b1, hq_c, nullptr, nullptr, stats2, mod, r0, 16384, 768, 192);
        gemm_k<0, 3><<<dim3(256, 3), 256, 0, stream>>>(
            hq_c, nullptr, w2T, b2, nullptr, dout, nullptr, nullptr, mod, r0, 16384, 192, 768);
    }
}